// Round 5
// baseline (942.350 us; speedup 1.0000x reference)
//
#include <hip/hip_runtime.h>

typedef _Float16 f16x8 __attribute__((ext_vector_type(8)));
typedef _Float16 f16x4 __attribute__((ext_vector_type(4)));
typedef float f32x4 __attribute__((ext_vector_type(4)));

#define S_DIM 8192
#define D_DIM 512

__device__ __forceinline__ float sigf(float x) { return 1.0f / (1.0f + __expf(-x)); }
__device__ __forceinline__ float tanhfast(float x) {
  return 1.0f - 2.0f / (__expf(2.0f * x) + 1.0f);
}

// ---------------------------------------------------------------------------
// Tile geometry (BK=64, XOR-swizzled LDS), unchanged from round 4:
//  * LDS tile: [rows][64 f16] = 128 B/row; 16-B chunk c of row r stored at
//    slot (c ^ (r&7)).  LDS writes are lane-linear; the global SOURCE address
//    is pre-swizzled (rule #21): region m = 8 rows = 1024 B, lane l handles
//    row 8m+(l>>3), global chunk (l&7)^(l>>3).
//  * Fragment read: row r, chunk c = h*4 + (lane>>4),
//    LDS elem = r*64 + ((c ^ (r&7))<<3) -> 8 banks x 2 lanes = conflict-free.
// Round-5 change: T14 async-STAGE split. Loads for tile t+1 are issued to
// REGISTERS before the MFMA cluster of tile t (latency hides under compute);
// regs -> ds_write after the post-compute barrier. Same LDS footprint.
// ---------------------------------------------------------------------------

// C[m][n] = sum_k A[m][k] * B[n][k];  A:[M x K] lda, B:[N x K] ldb, C fp16 ldc.
// grid = (N/BN, M/BM), 256 threads.
template <int BM, int BN>
__global__ __launch_bounds__(256) void gemm_bt(const _Float16* __restrict__ A, int lda,
                                               const _Float16* __restrict__ B, int ldb,
                                               _Float16* __restrict__ C, int ldc, int K) {
  constexpr int BK = 64;
  constexpr int FM = BM / 32, FN = BN / 32;
  constexpr int PA = BM / 32, PB = BN / 32;
  __shared__ _Float16 As[BM * BK];
  __shared__ _Float16 Bs[BN * BK];
  const int tid = threadIdx.x;
  const int lane = tid & 63;
  const int wv = tid >> 6;
  const int bm = blockIdx.y * BM;
  const int bn = blockIdx.x * BN;
  const int wm = (wv >> 1) * (BM / 2);
  const int wn = (wv & 1) * (BN / 2);
  const int fr = lane & 15;
  const int hi4 = lane >> 4;
  const int rx7 = fr & 7;
  const int srow = lane >> 3;
  const int schk = (lane & 7) ^ srow;

  const _Float16* Ab = A + (size_t)(bm + srow) * lda + schk * 8;
  const _Float16* Bb = B + (size_t)(bn + srow) * ldb + schk * 8;

  f32x4 ra[PA], rb[PB];
  auto load_ab = [&](int kt) {
#pragma unroll
    for (int p = 0; p < PA; ++p)
      ra[p] = *(const f32x4*)(Ab + (size_t)(8 * (wv + 4 * p)) * lda + kt);
#pragma unroll
    for (int p = 0; p < PB; ++p)
      rb[p] = *(const f32x4*)(Bb + (size_t)(8 * (wv + 4 * p)) * ldb + kt);
  };
  auto write_ab = [&]() {
#pragma unroll
    for (int p = 0; p < PA; ++p) *((f32x4*)(As + 512 * (wv + 4 * p)) + lane) = ra[p];
#pragma unroll
    for (int p = 0; p < PB; ++p) *((f32x4*)(Bs + 512 * (wv + 4 * p)) + lane) = rb[p];
  };

  f32x4 acc[FM][FN] = {};

  load_ab(0);
  write_ab();
  __syncthreads();

  for (int kt = 0; kt < K; kt += BK) {
    const bool more = (kt + BK) < K;
    if (more) load_ab(kt + BK);  // issue next tile early; flies under MFMA

#pragma unroll
    for (int h = 0; h < 2; ++h) {
      const int co = (((h << 2) | hi4) ^ rx7) << 3;
      f16x8 af[FM], bf[FN];
#pragma unroll
      for (int i = 0; i < FM; ++i)
        af[i] = *(const f16x8*)&As[(wm + i * 16 + fr) * 64 + co];
#pragma unroll
      for (int j = 0; j < FN; ++j)
        bf[j] = *(const f16x8*)&Bs[(wn + j * 16 + fr) * 64 + co];
#pragma unroll
      for (int i = 0; i < FM; ++i)
#pragma unroll
        for (int j = 0; j < FN; ++j)
          acc[i][j] = __builtin_amdgcn_mfma_f32_16x16x32_f16(af[i], bf[j], acc[i][j], 0, 0, 0);
    }
    __syncthreads();  // all waves' ds_reads of tile t done
    if (more) {
      write_ab();      // vmcnt wait lands here, after compute
      __syncthreads(); // staged tile visible
    }
  }

  const int cc = lane & 15;
  const int cr = (lane >> 4) * 4;
#pragma unroll
  for (int i = 0; i < FM; ++i)
#pragma unroll
    for (int j = 0; j < FN; ++j) {
      size_t base = (size_t)(bm + wm + i * 16 + cr) * ldc + (bn + wn + j * 16 + cc);
#pragma unroll
      for (int r = 0; r < 4; ++r) C[base + (size_t)r * ldc] = (_Float16)acc[i][j][r];
    }
}

// Split-K readout partials: partial_kc = P[:, kc*1024:+1024] @ g-chunk.
// A = P fp16 (lda 16384, first half of each P32 row slot), B = gT (ldb 8192).
// Partial (f32) stored in the DEAD second half of each P32 row slot.
// grid (32 mb, 8 nb, 8 kc): x=mb so A-panel sharers (same mb,kc) share an XCD.
__global__ __launch_bounds__(256) void gemm_rsplit(const _Float16* __restrict__ A,
                                                   const _Float16* __restrict__ B,
                                                   float* __restrict__ Ppart) {
  constexpr int BK = 64;
  __shared__ _Float16 As[64 * BK];
  __shared__ _Float16 Bs[64 * BK];
  const int tid = threadIdx.x;
  const int lane = tid & 63;
  const int wv = tid >> 6;
  const int bm = blockIdx.x * 64;
  const int bn = blockIdx.y * 64;
  const int kc = blockIdx.z;
  const int k0 = kc * 1024;
  const int wm = (wv >> 1) * 32;
  const int wn = (wv & 1) * 32;
  const int fr = lane & 15;
  const int hi4 = lane >> 4;
  const int rx7 = fr & 7;
  const int srow = lane >> 3;
  const int schk = (lane & 7) ^ srow;

  const _Float16* Ab = A + (size_t)(bm + srow) * 16384 + schk * 8;
  const _Float16* Bb = B + (size_t)(bn + srow) * 8192 + schk * 8;

  f32x4 ra[2], rb[2];
  auto load_ab = [&](int kt) {
#pragma unroll
    for (int p = 0; p < 2; ++p) {
      ra[p] = *(const f32x4*)(Ab + (size_t)(8 * (wv + 4 * p)) * 16384 + kt);
      rb[p] = *(const f32x4*)(Bb + (size_t)(8 * (wv + 4 * p)) * 8192 + kt);
    }
  };
  auto write_ab = [&]() {
#pragma unroll
    for (int p = 0; p < 2; ++p) {
      *((f32x4*)(As + 512 * (wv + 4 * p)) + lane) = ra[p];
      *((f32x4*)(Bs + 512 * (wv + 4 * p)) + lane) = rb[p];
    }
  };

  f32x4 acc[2][2] = {};

  load_ab(k0);
  write_ab();
  __syncthreads();

  for (int kt = k0; kt < k0 + 1024; kt += BK) {
    const bool more = (kt + BK) < (k0 + 1024);
    if (more) load_ab(kt + BK);

#pragma unroll
    for (int h = 0; h < 2; ++h) {
      const int co = (((h << 2) | hi4) ^ rx7) << 3;
      f16x8 af[2], bf[2];
#pragma unroll
      for (int i = 0; i < 2; ++i) {
        af[i] = *(const f16x8*)&As[(wm + i * 16 + fr) * 64 + co];
        bf[i] = *(const f16x8*)&Bs[(wn + i * 16 + fr) * 64 + co];
      }
#pragma unroll
      for (int i = 0; i < 2; ++i)
#pragma unroll
        for (int j = 0; j < 2; ++j)
          acc[i][j] = __builtin_amdgcn_mfma_f32_16x16x32_f16(af[i], bf[j], acc[i][j], 0, 0, 0);
    }
    __syncthreads();
    if (more) {
      write_ab();
      __syncthreads();
    }
  }

  const int cc = lane & 15;
  const int cr = (lane >> 4) * 4;
#pragma unroll
  for (int i = 0; i < 2; ++i)
#pragma unroll
    for (int j = 0; j < 2; ++j) {
      size_t base = (size_t)(bm + wm + i * 16 + cr) * 8192 + 4096 + (size_t)kc * 512 +
                    (bn + wn + j * 16 + cc);
#pragma unroll
      for (int r = 0; r < 4; ++r) Ppart[base + (size_t)r * 8192] = acc[i][j][r];
    }
}

// r[m][n] = sum_kc partial[kc][m][n]; write fp16 into concat r-slot (ld 1024).
__global__ __launch_bounds__(256) void reduce_r(const float* __restrict__ Ppart,
                                                _Float16* __restrict__ rout) {
  int idx = blockIdx.x * 256 + threadIdx.x;  // 0 .. 2048*128-1
  int m = idx >> 7;
  int n4 = (idx & 127) * 4;
  const float* base = Ppart + (size_t)m * 8192 + 4096 + n4;
  f32x4 s = {0.f, 0.f, 0.f, 0.f};
#pragma unroll
  for (int kc = 0; kc < 8; ++kc) s += *(const f32x4*)(base + kc * 512);
  f16x4 h = {(_Float16)s[0], (_Float16)s[1], (_Float16)s[2], (_Float16)s[3]};
  *(f16x4*)&rout[(size_t)m * 1024 + n4] = h;
}

// Split-fp16 scores GEMM (2-term): C(f32) = (Ah+Al) @ Bh^T  (h_hi*g + h_lo*g).
// BM=BN=128, K=512. grid (64, M/128).
__global__ __launch_bounds__(256) void gemm_scores(const _Float16* __restrict__ Ah, int ldah,
                                                   const _Float16* __restrict__ Al,
                                                   const _Float16* __restrict__ Bh,
                                                   float* __restrict__ C) {
  constexpr int BK = 64;
  __shared__ _Float16 AsH[128 * BK];
  __shared__ _Float16 AsL[128 * BK];
  __shared__ _Float16 BsH[128 * BK];
  const int tid = threadIdx.x;
  const int lane = tid & 63;
  const int wv = tid >> 6;
  const int bm = blockIdx.y * 128;
  const int bn = blockIdx.x * 128;
  const int wm = (wv >> 1) * 64;
  const int wn = (wv & 1) * 64;
  const int fr = lane & 15;
  const int hi4 = lane >> 4;
  const int rx7 = fr & 7;
  const int srow = lane >> 3;
  const int schk = (lane & 7) ^ srow;

  const _Float16* Ahb = Ah + (size_t)(bm + srow) * ldah + schk * 8;
  const _Float16* Alb = Al + (size_t)(bm + srow) * 512 + schk * 8;
  const _Float16* Bhb = Bh + (size_t)(bn + srow) * 512 + schk * 8;

  f32x4 rah[4], ral[4], rbh[4];
  auto load_all = [&](int kt) {
#pragma unroll
    for (int p = 0; p < 4; ++p) {
      const size_t m8 = (size_t)(8 * (wv + 4 * p));
      rah[p] = *(const f32x4*)(Ahb + m8 * ldah + kt);
      ral[p] = *(const f32x4*)(Alb + m8 * 512 + kt);
      rbh[p] = *(const f32x4*)(Bhb + m8 * 512 + kt);
    }
  };
  auto write_all = [&]() {
#pragma unroll
    for (int p = 0; p < 4; ++p) {
      const int m = wv + 4 * p;
      *((f32x4*)(AsH + 512 * m) + lane) = rah[p];
      *((f32x4*)(AsL + 512 * m) + lane) = ral[p];
      *((f32x4*)(BsH + 512 * m) + lane) = rbh[p];
    }
  };

  f32x4 acc[4][4] = {};

  load_all(0);
  write_all();
  __syncthreads();

  for (int kt = 0; kt < 512; kt += BK) {
    const bool more = (kt + BK) < 512;
    if (more) load_all(kt + BK);

#pragma unroll
    for (int h = 0; h < 2; ++h) {
      const int co = (((h << 2) | hi4) ^ rx7) << 3;
      f16x8 fah[4], fal[4], fbh[4];
#pragma unroll
      for (int i = 0; i < 4; ++i) {
        fah[i] = *(const f16x8*)&AsH[(wm + i * 16 + fr) * 64 + co];
        fal[i] = *(const f16x8*)&AsL[(wm + i * 16 + fr) * 64 + co];
        fbh[i] = *(const f16x8*)&BsH[(wn + i * 16 + fr) * 64 + co];
      }
#pragma unroll
      for (int i = 0; i < 4; ++i)
#pragma unroll
        for (int j = 0; j < 4; ++j) {
          acc[i][j] = __builtin_amdgcn_mfma_f32_16x16x32_f16(fah[i], fbh[j], acc[i][j], 0, 0, 0);
          acc[i][j] = __builtin_amdgcn_mfma_f32_16x16x32_f16(fal[i], fbh[j], acc[i][j], 0, 0, 0);
        }
    }
    __syncthreads();
    if (more) {
      write_all();
      __syncthreads();
    }
  }

  const int cc = lane & 15;
  const int cr = (lane >> 4) * 4;
#pragma unroll
  for (int i = 0; i < 4; ++i)
#pragma unroll
    for (int j = 0; j < 4; ++j) {
      size_t base = (size_t)(bm + wm + i * 16 + cr) * 8192 + (bn + wn + j * 16 + cc);
#pragma unroll
      for (int r = 0; r < 4; ++r) C[base + (size_t)r * 8192] = acc[i][j][r];
    }
}

// transpose g [8192x512] f32 -> gT [512x8192] f16; also g_hi f16
__global__ __launch_bounds__(256) void prep_g(const float* __restrict__ g,
                                              _Float16* __restrict__ gT,
                                              _Float16* __restrict__ g_h) {
  __shared__ _Float16 tile[64][72];
  const int s0 = blockIdx.x * 64;
  const int d0 = blockIdx.y * 64;
  const int t = threadIdx.x;
  const int r = t >> 2;
  const int cq = (t & 3) * 16;
  alignas(16) _Float16 buf[16];
#pragma unroll
  for (int q = 0; q < 4; ++q) {
    f32x4 v = *(const f32x4*)&g[(size_t)(s0 + r) * D_DIM + d0 + cq + q * 4];
#pragma unroll
    for (int e = 0; e < 4; ++e) buf[q * 4 + e] = (_Float16)v[e];
  }
#pragma unroll
  for (int k = 0; k < 16; ++k) tile[r][cq + k] = buf[k];
  *(f16x8*)&g_h[(size_t)(s0 + r) * D_DIM + d0 + cq] = *(const f16x8*)&buf[0];
  *(f16x8*)&g_h[(size_t)(s0 + r) * D_DIM + d0 + cq + 8] = *(const f16x8*)&buf[8];
  __syncthreads();
  alignas(16) _Float16 ob[16];
#pragma unroll
  for (int k = 0; k < 16; ++k) ob[k] = tile[cq + k][r];
  *(f16x8*)&gT[(size_t)(d0 + r) * S_DIM + s0 + cq] = *(const f16x8*)&ob[0];
  *(f16x8*)&gT[(size_t)(d0 + r) * S_DIM + s0 + cq + 8] = *(const f16x8*)&ob[8];
}

// convert W_ih, W_hh to f16; init concat[:, :512]=f16(f_x), h_lo=residual; zero c
__global__ __launch_bounds__(256) void prep_misc(const float* __restrict__ W_ih,
                                                 const float* __restrict__ W_hh,
                                                 const float* __restrict__ f_x,
                                                 _Float16* __restrict__ wih_h,
                                                 _Float16* __restrict__ whh_h,
                                                 _Float16* __restrict__ concat,
                                                 _Float16* __restrict__ h_lo,
                                                 float* __restrict__ c) {
  const int NW1 = 2048 * 512 / 4;
  const int NW2 = 2048 * 1024 / 4;
  const int NFX = 4096 * 512 / 4;
  int idx = blockIdx.x * 256 + threadIdx.x;
  if (idx < NW1) {
    f32x4 v = ((const f32x4*)W_ih)[idx];
    f16x4 h = {(_Float16)v[0], (_Float16)v[1], (_Float16)v[2], (_Float16)v[3]};
    ((f16x4*)wih_h)[idx] = h;
  } else if (idx < NW1 + NW2) {
    int k = idx - NW1;
    f32x4 v = ((const f32x4*)W_hh)[k];
    f16x4 h = {(_Float16)v[0], (_Float16)v[1], (_Float16)v[2], (_Float16)v[3]};
    ((f16x4*)whh_h)[k] = h;
  } else if (idx < NW1 + NW2 + NFX) {
    int k = idx - NW1 - NW2;
    f32x4 v = ((const f32x4*)f_x)[k];
    f16x4 h, lo;
#pragma unroll
    for (int e = 0; e < 4; ++e) {
      h[e] = (_Float16)v[e];
      lo[e] = (_Float16)(v[e] - (float)h[e]);
    }
    int m = k >> 7, j4 = k & 127;
    ((f16x4*)concat)[m * 256 + j4] = h;
    ((f16x4*)h_lo)[k] = lo;
    f32x4 z = {0.f, 0.f, 0.f, 0.f};
    ((f32x4*)c)[k] = z;
  }
}

// row softmax: read fp32 scores (8192), write fp16 probs in place (first half
// of the row's 32KB slot). One block per row; race-free in-place convert.
__global__ __launch_bounds__(256) void softmax_inplace(float* __restrict__ P) {
  float* p = P + (size_t)blockIdx.x * S_DIM;
  const int tid = threadIdx.x, lane = tid & 63, wave = tid >> 6;
  __shared__ float red[8];
  float x[32];
#pragma unroll
  for (int i = 0; i < 8; ++i) {
    f32x4 v = *(const f32x4*)&p[i * 1024 + tid * 4];
#pragma unroll
    for (int j = 0; j < 4; ++j) x[i * 4 + j] = v[j];
  }
  float m = -3.0e38f;
#pragma unroll
  for (int k = 0; k < 32; ++k) m = fmaxf(m, x[k]);
#pragma unroll
  for (int o = 32; o; o >>= 1) m = fmaxf(m, __shfl_xor(m, o));
  if (lane == 0) red[wave] = m;
  __syncthreads();
  m = fmaxf(fmaxf(red[0], red[1]), fmaxf(red[2], red[3]));
  float s = 0.f;
#pragma unroll
  for (int k = 0; k < 32; ++k) {
    x[k] = exp2f((x[k] - m) * 1.44269504f);
    s += x[k];
  }
#pragma unroll
  for (int o = 32; o; o >>= 1) s += __shfl_xor(s, o);
  if (lane == 0) red[4 + wave] = s;
  __syncthreads();
  s = (red[4] + red[5]) + (red[6] + red[7]);
  float inv = 1.0f / s;
  _Float16* out = (_Float16*)p;
#pragma unroll
  for (int i = 0; i < 8; ++i) {
    f16x4 v;
#pragma unroll
    for (int j = 0; j < 4; ++j) v[j] = (_Float16)(x[i * 4 + j] * inv);
    *(f16x4*)&out[i * 1024 + tid * 4] = v;
  }
}

// gates -> c,h update; writes c (f32), concat h-slot + h_lo (f16), hout (f32)
__global__ __launch_bounds__(256) void lstm_step(const _Float16* __restrict__ gmm,
                                                 const _Float16* __restrict__ gbase,
                                                 const float* __restrict__ b_ih,
                                                 const float* __restrict__ b_hh,
                                                 const float* __restrict__ f_x,
                                                 float* __restrict__ c,
                                                 _Float16* __restrict__ concat,
                                                 _Float16* __restrict__ h_lo,
                                                 float* __restrict__ hout) {
  int idx = blockIdx.x * 256 + threadIdx.x;  // 0 .. 4096*512/4-1
  int m = idx >> 7;
  int j = (idx & 127) * 4;
  size_t grow = (size_t)m * 2048 + j;
  f16x4 gI = *(const f16x4*)&gmm[grow];
  f16x4 gF = *(const f16x4*)&gmm[grow + 512];
  f16x4 gG = *(const f16x4*)&gmm[grow + 1024];
  f16x4 gO = *(const f16x4*)&gmm[grow + 1536];
  f16x4 aI = *(const f16x4*)&gbase[grow];
  f16x4 aF = *(const f16x4*)&gbase[grow + 512];
  f16x4 aG = *(const f16x4*)&gbase[grow + 1024];
  f16x4 aO = *(const f16x4*)&gbase[grow + 1536];
  f32x4 biI = *(const f32x4*)&b_ih[j];
  f32x4 biF = *(const f32x4*)&b_ih[j + 512];
  f32x4 biG = *(const f32x4*)&b_ih[j + 1024];
  f32x4 biO = *(const f32x4*)&b_ih[j + 1536];
  f32x4 bhI = *(const f32x4*)&b_hh[j];
  f32x4 bhF = *(const f32x4*)&b_hh[j + 512];
  f32x4 bhG = *(const f32x4*)&b_hh[j + 1024];
  f32x4 bhO = *(const f32x4*)&b_hh[j + 1536];
  f32x4 cv = ((const f32x4*)c)[idx];
  f32x4 fx = ((const f32x4*)f_x)[idx];
  f32x4 cn, hn;
  f16x4 h16, l16;
#pragma unroll
  for (int k = 0; k < 4; ++k) {
    float gi = (float)gI[k] + (float)aI[k] + biI[k] + bhI[k];
    float gf = (float)gF[k] + (float)aF[k] + biF[k] + bhF[k];
    float gg = (float)gG[k] + (float)aG[k] + biG[k] + bhG[k];
    float go = (float)gO[k] + (float)aO[k] + biO[k] + bhO[k];
    float ci = sigf(gf) * cv[k] + sigf(gi) * tanhfast(gg);
    float hi = sigf(go) * tanhfast(ci) + fx[k];
    cn[k] = ci;
    hn[k] = hi;
    h16[k] = (_Float16)hi;
    l16[k] = (_Float16)(hi - (float)h16[k]);
  }
  ((f32x4*)c)[idx] = cn;
  ((f32x4*)hout)[idx] = hn;
  ((f16x4*)concat)[m * 256 + (idx & 127)] = h16;
  ((f16x4*)h_lo)[idx] = l16;
}

extern "C" void kernel_launch(void* const* d_in, const int* in_sizes, int n_in,
                              void* d_out, int out_size, void* d_ws, size_t ws_size,
                              hipStream_t stream) {
  const float* f_x = (const float*)d_in[0];   // [4096,512]
  const float* g_S = (const float*)d_in[1];   // [8192,512]
  const float* W_ih = (const float*)d_in[2];  // [2048,512]
  const float* W_hh = (const float*)d_in[3];  // [2048,1024]
  const float* b_ih = (const float*)d_in[4];  // [2048]
  const float* b_hh = (const float*)d_in[5];  // [2048]
  float* hout = (float*)d_out;                // [4096,512]

  char* w = (char*)d_ws;
  float* P32 = (float*)w;                              // 2048*8192*4   = 67108864 (half-batch)
  _Float16* gates = (_Float16*)w;                      // alias P32 (dead by gates GEMM)
  _Float16* gbase = (_Float16*)(w + 67108864);         // 4096*2048*2   = 16777216
  _Float16* concat = (_Float16*)(w + 83886080);        // 4096*1024*2   = 8388608
  _Float16* g_h = (_Float16*)(w + 92274688);           // 8192*512*2    = 8388608
  _Float16* gT = (_Float16*)(w + 109051904);           // 512*8192*2    = 8388608
  _Float16* wih_h = (_Float16*)(w + 117440512);        // 2048*512*2    = 2097152
  _Float16* whh_h = (_Float16*)(w + 119537664);        // 2048*1024*2   = 4194304
  float* c = (float*)(w + 123731968);                  // 4096*512*4    = 8388608
  _Float16* h_lo = (_Float16*)(w + 132120576);         // 4096*512*2    = 4194304
  // total 136314880 bytes

  prep_g<<<dim3(S_DIM / 64, D_DIM / 64), 256, 0, stream>>>(g_S, gT, g_h);
  prep_misc<<<5120, 256, 0, stream>>>(W_ih, W_hh, f_x, wih_h, whh_h, concat, h_lo, c);

  // gbase = f_x @ W_ih^T  (A = concat[:, :512] which holds f16(f_x))
  gemm_bt<128, 128><<<dim3(2048 / 128, 4096 / 128), 256, 0, stream>>>(
      concat, 1024, wih_h, 512, gbase, 2048, 512);

  for (int it = 0; it < 4; ++it) {
    for (int hb = 0; hb < 2; ++hb) {
      const _Float16* hhi = concat + (size_t)hb * 2048 * 1024;
      const _Float16* hlo = h_lo + (size_t)hb * 2048 * 512;
      // scores = h @ g^T : [2048 x 8192] fp32, split-fp16 2-term
      gemm_scores<<<dim3(64, 16), 256, 0, stream>>>(hhi, 1024, hlo, g_h, P32);
      softmax_inplace<<<2048, 256, 0, stream>>>(P32);
      // r = P @ g, split-K=8 partials into dead second halves of P32 rows
      gemm_rsplit<<<dim3(32, 8, 8), 256, 0, stream>>>((const _Float16*)P32, gT, P32);
      // sum partials -> concat[:, 512:]
      reduce_r<<<1024, 256, 0, stream>>>(P32, concat + (size_t)hb * 2048 * 1024 + 512);
    }
    // gates_mm = concat @ W_hh^T : [4096 x 2048]
    gemm_bt<128, 128><<<dim3(2048 / 128, 4096 / 128), 256, 0, stream>>>(
        concat, 1024, whh_h, 1024, gates, 2048, 1024);
    lstm_step<<<2048, 256, 0, stream>>>(gates, gbase, b_ih, b_hh, f_x, c, concat, h_lo, hout);
  }
  (void)in_sizes; (void)n_in; (void)out_size; (void)ws_size;
}

// Round 6
// 870.833 us; speedup vs baseline: 1.0821x; 1.0821x over previous
//
#include <hip/hip_runtime.h>

typedef _Float16 f16x8 __attribute__((ext_vector_type(8)));
typedef _Float16 f16x4 __attribute__((ext_vector_type(4)));
typedef float f32x4 __attribute__((ext_vector_type(4)));

#define S_DIM 8192
#define D_DIM 512

__device__ __forceinline__ void gload_lds16(const _Float16* g, _Float16* l) {
  __builtin_amdgcn_global_load_lds(
      (const __attribute__((address_space(1))) unsigned int*)g,
      (__attribute__((address_space(3))) unsigned int*)l, 16, 0, 0);
}

__device__ __forceinline__ float sigf(float x) { return 1.0f / (1.0f + __expf(-x)); }
__device__ __forceinline__ float tanhfast(float x) {
  return 1.0f - 2.0f / (__expf(2.0f * x) + 1.0f);
}

// ---------------------------------------------------------------------------
// Tile geometry (BK=64, XOR-swizzled LDS), round-4 proven:
//  * LDS tile: [rows][64 f16] = 128 B/row; 16-B chunk c of row r stored at
//    slot (c ^ (r&7)).  Writes via global_load_lds stay lane-linear; the
//    global SOURCE is pre-swizzled (rule #21): region m = 8 rows = 1024 B,
//    lane l stages row 8m+(l>>3), global chunk (l&7)^(l>>3).
//  * Fragment read: row r, chunk c = h*4 + (lane>>4),
//    LDS elem = r*64 + ((c ^ (r&7))<<3) -> 8 banks x 2 lanes = conflict-free.
// Round-6: T14 reg-staging REVERTED (measured -5.5%: gload_lds wins here,
// per m151/m249).  rsplit retiled 64x64 -> 128x64.
// ---------------------------------------------------------------------------

// C[m][n] = sum_k A[m][k] * B[n][k];  A:[M x K] lda, B:[N x K] ldb, C fp16 ldc.
// grid = (N/BN, M/BM), 256 threads.
template <int BM, int BN>
__global__ __launch_bounds__(256) void gemm_bt(const _Float16* __restrict__ A, int lda,
                                               const _Float16* __restrict__ B, int ldb,
                                               _Float16* __restrict__ C, int ldc, int K) {
  constexpr int BK = 64;
  constexpr int FM = BM / 32, FN = BN / 32;
  __shared__ _Float16 As[BM * BK];
  __shared__ _Float16 Bs[BN * BK];
  const int tid = threadIdx.x;
  const int lane = tid & 63;
  const int wv = tid >> 6;
  const int bm = blockIdx.y * BM;
  const int bn = blockIdx.x * BN;
  const int wm = (wv >> 1) * (BM / 2);
  const int wn = (wv & 1) * (BN / 2);
  const int fr = lane & 15;
  const int hi4 = lane >> 4;
  const int rx7 = fr & 7;
  const int srow = lane >> 3;
  const int schk = (lane & 7) ^ srow;

  f32x4 acc[FM][FN] = {};

  for (int kt = 0; kt < K; kt += BK) {
    __syncthreads();  // previous tile's ds_reads done before overwrite
#pragma unroll
    for (int p = 0; p < BM / 32; ++p) {
      const int m = wv + 4 * p;
      gload_lds16(A + (size_t)(bm + 8 * m + srow) * lda + kt + schk * 8, As + 512 * m);
    }
#pragma unroll
    for (int p = 0; p < BN / 32; ++p) {
      const int m = wv + 4 * p;
      gload_lds16(B + (size_t)(bn + 8 * m + srow) * ldb + kt + schk * 8, Bs + 512 * m);
    }
    __syncthreads();  // staging visible (compiler drains vmcnt before barrier)

#pragma unroll
    for (int h = 0; h < 2; ++h) {
      const int co = (((h << 2) | hi4) ^ rx7) << 3;
      f16x8 af[FM], bf[FN];
#pragma unroll
      for (int i = 0; i < FM; ++i)
        af[i] = *(const f16x8*)&As[(wm + i * 16 + fr) * 64 + co];
#pragma unroll
      for (int j = 0; j < FN; ++j)
        bf[j] = *(const f16x8*)&Bs[(wn + j * 16 + fr) * 64 + co];
#pragma unroll
      for (int i = 0; i < FM; ++i)
#pragma unroll
        for (int j = 0; j < FN; ++j)
          acc[i][j] = __builtin_amdgcn_mfma_f32_16x16x32_f16(af[i], bf[j], acc[i][j], 0, 0, 0);
    }
  }

  const int cc = lane & 15;
  const int cr = (lane >> 4) * 4;
#pragma unroll
  for (int i = 0; i < FM; ++i)
#pragma unroll
    for (int j = 0; j < FN; ++j) {
      size_t base = (size_t)(bm + wm + i * 16 + cr) * ldc + (bn + wn + j * 16 + cc);
#pragma unroll
      for (int r = 0; r < 4; ++r) C[base + (size_t)r * ldc] = (_Float16)acc[i][j][r];
    }
}

// Split-K readout partials: partial_kc = P[:, kc*1024:+1024] @ g-chunk.
// A = P fp16 (lda 16384, first half of each P32 row slot), B = gT (ldb 8192).
// Partial (f32) stored in the DEAD second half of each P32 row slot.
// BM=128, BN=64. grid (16 mb, 8 nb, 8 kc): nb-sharers of an A-panel have
// linear-id stride 16 == 0 mod 8 -> same XCD (A reused in that L2).
__global__ __launch_bounds__(256) void gemm_rsplit(const _Float16* __restrict__ A,
                                                   const _Float16* __restrict__ B,
                                                   float* __restrict__ Ppart) {
  constexpr int BK = 64;
  __shared__ _Float16 As[128 * BK];
  __shared__ _Float16 Bs[64 * BK];
  const int tid = threadIdx.x;
  const int lane = tid & 63;
  const int wv = tid >> 6;
  const int bm = blockIdx.x * 128;
  const int bn = blockIdx.y * 64;
  const int kc = blockIdx.z;
  const int k0 = kc * 1024;
  const int wm = (wv >> 1) * 64;
  const int wn = (wv & 1) * 32;
  const int fr = lane & 15;
  const int hi4 = lane >> 4;
  const int rx7 = fr & 7;
  const int srow = lane >> 3;
  const int schk = (lane & 7) ^ srow;

  f32x4 acc[4][2] = {};

  for (int kt = k0; kt < k0 + 1024; kt += BK) {
    __syncthreads();
#pragma unroll
    for (int p = 0; p < 4; ++p) {
      const int m = wv + 4 * p;
      gload_lds16(A + (size_t)(bm + 8 * m + srow) * 16384 + kt + schk * 8, As + 512 * m);
    }
#pragma unroll
    for (int p = 0; p < 2; ++p) {
      const int m = wv + 4 * p;
      gload_lds16(B + (size_t)(bn + 8 * m + srow) * 8192 + kt + schk * 8, Bs + 512 * m);
    }
    __syncthreads();

#pragma unroll
    for (int h = 0; h < 2; ++h) {
      const int co = (((h << 2) | hi4) ^ rx7) << 3;
      f16x8 af[4], bf[2];
#pragma unroll
      for (int i = 0; i < 4; ++i)
        af[i] = *(const f16x8*)&As[(wm + i * 16 + fr) * 64 + co];
#pragma unroll
      for (int j = 0; j < 2; ++j)
        bf[j] = *(const f16x8*)&Bs[(wn + j * 16 + fr) * 64 + co];
#pragma unroll
      for (int i = 0; i < 4; ++i)
#pragma unroll
        for (int j = 0; j < 2; ++j)
          acc[i][j] = __builtin_amdgcn_mfma_f32_16x16x32_f16(af[i], bf[j], acc[i][j], 0, 0, 0);
    }
  }

  const int cc = lane & 15;
  const int cr = (lane >> 4) * 4;
#pragma unroll
  for (int i = 0; i < 4; ++i)
#pragma unroll
    for (int j = 0; j < 2; ++j) {
      size_t base = (size_t)(bm + wm + i * 16 + cr) * 8192 + 4096 + (size_t)kc * 512 +
                    (bn + wn + j * 16 + cc);
#pragma unroll
      for (int r = 0; r < 4; ++r) Ppart[base + (size_t)r * 8192] = acc[i][j][r];
    }
}

// r[m][n] = sum_kc partial[kc][m][n]; write fp16 into concat r-slot (ld 1024).
__global__ __launch_bounds__(256) void reduce_r(const float* __restrict__ Ppart,
                                                _Float16* __restrict__ rout) {
  int idx = blockIdx.x * 256 + threadIdx.x;  // 0 .. 2048*128-1
  int m = idx >> 7;
  int n4 = (idx & 127) * 4;
  const float* base = Ppart + (size_t)m * 8192 + 4096 + n4;
  f32x4 s = {0.f, 0.f, 0.f, 0.f};
#pragma unroll
  for (int kc = 0; kc < 8; ++kc) s += *(const f32x4*)(base + kc * 512);
  f16x4 h = {(_Float16)s[0], (_Float16)s[1], (_Float16)s[2], (_Float16)s[3]};
  *(f16x4*)&rout[(size_t)m * 1024 + n4] = h;
}

// Split-fp16 scores GEMM (2-term): C(f32) = (Ah+Al) @ Bh^T  (h_hi*g + h_lo*g).
// BM=BN=128, K=512. grid (64, M/128).
__global__ __launch_bounds__(256) void gemm_scores(const _Float16* __restrict__ Ah, int ldah,
                                                   const _Float16* __restrict__ Al,
                                                   const _Float16* __restrict__ Bh,
                                                   float* __restrict__ C) {
  constexpr int BK = 64;
  __shared__ _Float16 AsH[128 * BK];
  __shared__ _Float16 AsL[128 * BK];
  __shared__ _Float16 BsH[128 * BK];
  const int tid = threadIdx.x;
  const int lane = tid & 63;
  const int wv = tid >> 6;
  const int bm = blockIdx.y * 128;
  const int bn = blockIdx.x * 128;
  const int wm = (wv >> 1) * 64;
  const int wn = (wv & 1) * 64;
  const int fr = lane & 15;
  const int hi4 = lane >> 4;
  const int rx7 = fr & 7;
  const int srow = lane >> 3;
  const int schk = (lane & 7) ^ srow;

  f32x4 acc[4][4] = {};

  for (int kt = 0; kt < 512; kt += BK) {
    __syncthreads();
#pragma unroll
    for (int p = 0; p < 4; ++p) {
      const int m = wv + 4 * p;
      const int row = 8 * m + srow;
      gload_lds16(Ah + (size_t)(bm + row) * ldah + kt + schk * 8, AsH + 512 * m);
      gload_lds16(Al + (size_t)(bm + row) * 512 + kt + schk * 8, AsL + 512 * m);
      gload_lds16(Bh + (size_t)(bn + row) * 512 + kt + schk * 8, BsH + 512 * m);
    }
    __syncthreads();

#pragma unroll
    for (int h = 0; h < 2; ++h) {
      const int co = (((h << 2) | hi4) ^ rx7) << 3;
      f16x8 fah[4], fal[4], fbh[4];
#pragma unroll
      for (int i = 0; i < 4; ++i) {
        fah[i] = *(const f16x8*)&AsH[(wm + i * 16 + fr) * 64 + co];
        fal[i] = *(const f16x8*)&AsL[(wm + i * 16 + fr) * 64 + co];
        fbh[i] = *(const f16x8*)&BsH[(wn + i * 16 + fr) * 64 + co];
      }
#pragma unroll
      for (int i = 0; i < 4; ++i)
#pragma unroll
        for (int j = 0; j < 4; ++j) {
          acc[i][j] = __builtin_amdgcn_mfma_f32_16x16x32_f16(fah[i], fbh[j], acc[i][j], 0, 0, 0);
          acc[i][j] = __builtin_amdgcn_mfma_f32_16x16x32_f16(fal[i], fbh[j], acc[i][j], 0, 0, 0);
        }
    }
  }

  const int cc = lane & 15;
  const int cr = (lane >> 4) * 4;
#pragma unroll
  for (int i = 0; i < 4; ++i)
#pragma unroll
    for (int j = 0; j < 4; ++j) {
      size_t base = (size_t)(bm + wm + i * 16 + cr) * 8192 + (bn + wn + j * 16 + cc);
#pragma unroll
      for (int r = 0; r < 4; ++r) C[base + (size_t)r * 8192] = acc[i][j][r];
    }
}

// transpose g [8192x512] f32 -> gT [512x8192] f16; also g_hi f16
__global__ __launch_bounds__(256) void prep_g(const float* __restrict__ g,
                                              _Float16* __restrict__ gT,
                                              _Float16* __restrict__ g_h) {
  __shared__ _Float16 tile[64][72];
  const int s0 = blockIdx.x * 64;
  const int d0 = blockIdx.y * 64;
  const int t = threadIdx.x;
  const int r = t >> 2;
  const int cq = (t & 3) * 16;
  alignas(16) _Float16 buf[16];
#pragma unroll
  for (int q = 0; q < 4; ++q) {
    f32x4 v = *(const f32x4*)&g[(size_t)(s0 + r) * D_DIM + d0 + cq + q * 4];
#pragma unroll
    for (int e = 0; e < 4; ++e) buf[q * 4 + e] = (_Float16)v[e];
  }
#pragma unroll
  for (int k = 0; k < 16; ++k) tile[r][cq + k] = buf[k];
  *(f16x8*)&g_h[(size_t)(s0 + r) * D_DIM + d0 + cq] = *(const f16x8*)&buf[0];
  *(f16x8*)&g_h[(size_t)(s0 + r) * D_DIM + d0 + cq + 8] = *(const f16x8*)&buf[8];
  __syncthreads();
  alignas(16) _Float16 ob[16];
#pragma unroll
  for (int k = 0; k < 16; ++k) ob[k] = tile[cq + k][r];
  *(f16x8*)&gT[(size_t)(d0 + r) * S_DIM + s0 + cq] = *(const f16x8*)&ob[0];
  *(f16x8*)&gT[(size_t)(d0 + r) * S_DIM + s0 + cq + 8] = *(const f16x8*)&ob[8];
}

// convert W_ih, W_hh to f16; init concat[:, :512]=f16(f_x), h_lo=residual; zero c
__global__ __launch_bounds__(256) void prep_misc(const float* __restrict__ W_ih,
                                                 const float* __restrict__ W_hh,
                                                 const float* __restrict__ f_x,
                                                 _Float16* __restrict__ wih_h,
                                                 _Float16* __restrict__ whh_h,
                                                 _Float16* __restrict__ concat,
                                                 _Float16* __restrict__ h_lo,
                                                 float* __restrict__ c) {
  const int NW1 = 2048 * 512 / 4;
  const int NW2 = 2048 * 1024 / 4;
  const int NFX = 4096 * 512 / 4;
  int idx = blockIdx.x * 256 + threadIdx.x;
  if (idx < NW1) {
    f32x4 v = ((const f32x4*)W_ih)[idx];
    f16x4 h = {(_Float16)v[0], (_Float16)v[1], (_Float16)v[2], (_Float16)v[3]};
    ((f16x4*)wih_h)[idx] = h;
  } else if (idx < NW1 + NW2) {
    int k = idx - NW1;
    f32x4 v = ((const f32x4*)W_hh)[k];
    f16x4 h = {(_Float16)v[0], (_Float16)v[1], (_Float16)v[2], (_Float16)v[3]};
    ((f16x4*)whh_h)[k] = h;
  } else if (idx < NW1 + NW2 + NFX) {
    int k = idx - NW1 - NW2;
    f32x4 v = ((const f32x4*)f_x)[k];
    f16x4 h, lo;
#pragma unroll
    for (int e = 0; e < 4; ++e) {
      h[e] = (_Float16)v[e];
      lo[e] = (_Float16)(v[e] - (float)h[e]);
    }
    int m = k >> 7, j4 = k & 127;
    ((f16x4*)concat)[m * 256 + j4] = h;
    ((f16x4*)h_lo)[k] = lo;
    f32x4 z = {0.f, 0.f, 0.f, 0.f};
    ((f32x4*)c)[k] = z;
  }
}

// row softmax: read fp32 scores (8192), write fp16 probs in place (first half
// of the row's 32KB slot). One block per row; race-free in-place convert.
__global__ __launch_bounds__(256) void softmax_inplace(float* __restrict__ P) {
  float* p = P + (size_t)blockIdx.x * S_DIM;
  const int tid = threadIdx.x, lane = tid & 63, wave = tid >> 6;
  __shared__ float red[8];
  float x[32];
#pragma unroll
  for (int i = 0; i < 8; ++i) {
    f32x4 v = *(const f32x4*)&p[i * 1024 + tid * 4];
#pragma unroll
    for (int j = 0; j < 4; ++j) x[i * 4 + j] = v[j];
  }
  float m = -3.0e38f;
#pragma unroll
  for (int k = 0; k < 32; ++k) m = fmaxf(m, x[k]);
#pragma unroll
  for (int o = 32; o; o >>= 1) m = fmaxf(m, __shfl_xor(m, o));
  if (lane == 0) red[wave] = m;
  __syncthreads();
  m = fmaxf(fmaxf(red[0], red[1]), fmaxf(red[2], red[3]));
  float s = 0.f;
#pragma unroll
  for (int k = 0; k < 32; ++k) {
    x[k] = exp2f((x[k] - m) * 1.44269504f);
    s += x[k];
  }
#pragma unroll
  for (int o = 32; o; o >>= 1) s += __shfl_xor(s, o);
  if (lane == 0) red[4 + wave] = s;
  __syncthreads();
  s = (red[4] + red[5]) + (red[6] + red[7]);
  float inv = 1.0f / s;
  _Float16* out = (_Float16*)p;
#pragma unroll
  for (int i = 0; i < 8; ++i) {
    f16x4 v;
#pragma unroll
    for (int j = 0; j < 4; ++j) v[j] = (_Float16)(x[i * 4 + j] * inv);
    *(f16x4*)&out[i * 1024 + tid * 4] = v;
  }
}

// gates -> c,h update; writes c (f32), concat h-slot + h_lo (f16), hout (f32)
__global__ __launch_bounds__(256) void lstm_step(const _Float16* __restrict__ gmm,
                                                 const _Float16* __restrict__ gbase,
                                                 const float* __restrict__ b_ih,
                                                 const float* __restrict__ b_hh,
                                                 const float* __restrict__ f_x,
                                                 float* __restrict__ c,
                                                 _Float16* __restrict__ concat,
                                                 _Float16* __restrict__ h_lo,
                                                 float* __restrict__ hout) {
  int idx = blockIdx.x * 256 + threadIdx.x;  // 0 .. 4096*512/4-1
  int m = idx >> 7;
  int j = (idx & 127) * 4;
  size_t grow = (size_t)m * 2048 + j;
  f16x4 gI = *(const f16x4*)&gmm[grow];
  f16x4 gF = *(const f16x4*)&gmm[grow + 512];
  f16x4 gG = *(const f16x4*)&gmm[grow + 1024];
  f16x4 gO = *(const f16x4*)&gmm[grow + 1536];
  f16x4 aI = *(const f16x4*)&gbase[grow];
  f16x4 aF = *(const f16x4*)&gbase[grow + 512];
  f16x4 aG = *(const f16x4*)&gbase[grow + 1024];
  f16x4 aO = *(const f16x4*)&gbase[grow + 1536];
  f32x4 biI = *(const f32x4*)&b_ih[j];
  f32x4 biF = *(const f32x4*)&b_ih[j + 512];
  f32x4 biG = *(const f32x4*)&b_ih[j + 1024];
  f32x4 biO = *(const f32x4*)&b_ih[j + 1536];
  f32x4 bhI = *(const f32x4*)&b_hh[j];
  f32x4 bhF = *(const f32x4*)&b_hh[j + 512];
  f32x4 bhG = *(const f32x4*)&b_hh[j + 1024];
  f32x4 bhO = *(const f32x4*)&b_hh[j + 1536];
  f32x4 cv = ((const f32x4*)c)[idx];
  f32x4 fx = ((const f32x4*)f_x)[idx];
  f32x4 cn, hn;
  f16x4 h16, l16;
#pragma unroll
  for (int k = 0; k < 4; ++k) {
    float gi = (float)gI[k] + (float)aI[k] + biI[k] + bhI[k];
    float gf = (float)gF[k] + (float)aF[k] + biF[k] + bhF[k];
    float gg = (float)gG[k] + (float)aG[k] + biG[k] + bhG[k];
    float go = (float)gO[k] + (float)aO[k] + biO[k] + bhO[k];
    float ci = sigf(gf) * cv[k] + sigf(gi) * tanhfast(gg);
    float hi = sigf(go) * tanhfast(ci) + fx[k];
    cn[k] = ci;
    hn[k] = hi;
    h16[k] = (_Float16)hi;
    l16[k] = (_Float16)(hi - (float)h16[k]);
  }
  ((f32x4*)c)[idx] = cn;
  ((f32x4*)hout)[idx] = hn;
  ((f16x4*)concat)[m * 256 + (idx & 127)] = h16;
  ((f16x4*)h_lo)[idx] = l16;
}

extern "C" void kernel_launch(void* const* d_in, const int* in_sizes, int n_in,
                              void* d_out, int out_size, void* d_ws, size_t ws_size,
                              hipStream_t stream) {
  const float* f_x = (const float*)d_in[0];   // [4096,512]
  const float* g_S = (const float*)d_in[1];   // [8192,512]
  const float* W_ih = (const float*)d_in[2];  // [2048,512]
  const float* W_hh = (const float*)d_in[3];  // [2048,1024]
  const float* b_ih = (const float*)d_in[4];  // [2048]
  const float* b_hh = (const float*)d_in[5];  // [2048]
  float* hout = (float*)d_out;                // [4096,512]

  char* w = (char*)d_ws;
  float* P32 = (float*)w;                              // 2048*8192*4   = 67108864 (half-batch)
  _Float16* gates = (_Float16*)w;                      // alias P32 (dead by gates GEMM)
  _Float16* gbase = (_Float16*)(w + 67108864);         // 4096*2048*2   = 16777216
  _Float16* concat = (_Float16*)(w + 83886080);        // 4096*1024*2   = 8388608
  _Float16* g_h = (_Float16*)(w + 92274688);           // 8192*512*2    = 8388608
  _Float16* gT = (_Float16*)(w + 109051904);           // 512*8192*2    = 8388608
  _Float16* wih_h = (_Float16*)(w + 117440512);        // 2048*512*2    = 2097152
  _Float16* whh_h = (_Float16*)(w + 119537664);        // 2048*1024*2   = 4194304
  float* c = (float*)(w + 123731968);                  // 4096*512*4    = 8388608
  _Float16* h_lo = (_Float16*)(w + 132120576);         // 4096*512*2    = 4194304
  // total 136314880 bytes

  prep_g<<<dim3(S_DIM / 64, D_DIM / 64), 256, 0, stream>>>(g_S, gT, g_h);
  prep_misc<<<5120, 256, 0, stream>>>(W_ih, W_hh, f_x, wih_h, whh_h, concat, h_lo, c);

  // gbase = f_x @ W_ih^T  (A = concat[:, :512] which holds f16(f_x))
  gemm_bt<128, 128><<<dim3(2048 / 128, 4096 / 128), 256, 0, stream>>>(
      concat, 1024, wih_h, 512, gbase, 2048, 512);

  for (int it = 0; it < 4; ++it) {
    for (int hb = 0; hb < 2; ++hb) {
      const _Float16* hhi = concat + (size_t)hb * 2048 * 1024;
      const _Float16* hlo = h_lo + (size_t)hb * 2048 * 512;
      // scores = h @ g^T : [2048 x 8192] fp32, split-fp16 2-term
      gemm_scores<<<dim3(64, 16), 256, 0, stream>>>(hhi, 1024, hlo, g_h, P32);
      softmax_inplace<<<2048, 256, 0, stream>>>(P32);
      // r = P @ g, split-K=8 partials into dead second halves of P32 rows
      gemm_rsplit<<<dim3(16, 8, 8), 256, 0, stream>>>((const _Float16*)P32, gT, P32);
      // sum partials -> concat[:, 512:]
      reduce_r<<<1024, 256, 0, stream>>>(P32, concat + (size_t)hb * 2048 * 1024 + 512);
    }
    // gates_mm = concat @ W_hh^T : [4096 x 2048]
    gemm_bt<128, 128><<<dim3(2048 / 128, 4096 / 128), 256, 0, stream>>>(
        concat, 1024, whh_h, 1024, gates, 2048, 1024);
    lstm_step<<<2048, 256, 0, stream>>>(gates, gbase, b_ih, b_hh, f_x, c, concat, h_lo, hout);
  }
  (void)in_sizes; (void)n_in; (void)out_size; (void)ws_size;
}